// Round 7
// baseline (77.073 us; speedup 1.0000x reference)
//
#include <hip/hip_runtime.h>
#include <hip/hip_bf16.h>
#include <cstddef>
#include <cstdint>

#define KTAGS 64
#define DDIM  512
#define TLEN  128
#define BSEQ  512
#define SEQ   126          // real word positions t = 1..126
#define BOS_T 63
#define EOS_T 62
#define NITEMS (BSEQ * SEQ)   // 64512
#define NKS   (DDIM / 32)     // 16 K-steps of 32

typedef __attribute__((ext_vector_type(8))) short bf16x8;   // 8 bf16 = 4 VGPRs
typedef __attribute__((ext_vector_type(4))) float f32x4;
typedef __attribute__((ext_vector_type(4))) int   i32x4;

__device__ __forceinline__ short f2bf(float f) {
    uint32_t u = __float_as_uint(f);
    u += 0x7fffu + ((u >> 16) & 1u);       // RTNE
    return (short)(u >> 16);
}

// ---------------------------------------------------------------------------
// Kernel 0: pack ThetaB (f32 [64][512]) into bf16 MFMA B-frag order.
// frag idx = (ks*4+g)*64 + lane ; holds Th[g*16+(lane&15)][ks*32+(lane>>4)*8+j]
// ---------------------------------------------------------------------------
__global__ __launch_bounds__(256) void pack_theta_kernel(
    const float* __restrict__ Th, short* __restrict__ thp)
{
    int idx  = blockIdx.x * 256 + threadIdx.x;   // 0..4095
    int lane = idx & 63;
    int gg   = (idx >> 6) & 3;
    int ks   = idx >> 8;
    int tag  = gg * 16 + (lane & 15);
    int kb   = ks * 32 + (lane >> 4) * 8;
    const float* src = Th + (size_t)tag * DDIM + kb;
    short tmp[8];
    #pragma unroll
    for (int j = 0; j < 8; ++j) tmp[j] = f2bf(src[j]);
    *(i32x4*)(thp + (size_t)idx * 8) = *(const i32x4*)tmp;
}

// ---------------------------------------------------------------------------
// Kernel 1: e[(s/16)][t][s%16][tag] = exp(dot(E[words[s][t+1]], ThetaB[tag])).
// v2: each E row fetched as ONE contiguous 2 KB burst (64 lanes x 32 B),
// converted to bf16 in-register, staged in XOR-swizzled LDS; MFMA A-frags
// come from ds_read_b128. Waves are LDS-disjoint (no barriers).
// ---------------------------------------------------------------------------
__global__ __launch_bounds__(256) void emit_kernel(
    const float* __restrict__ E, const int* __restrict__ words,
    const short* __restrict__ thp, float* __restrict__ eout)
{
    __shared__ short srows[64 * 512];   // 64 KB: 64 bf16 rows, 1 KB each

    const int tid  = threadIdx.x;
    const int wave = tid >> 6;
    const int lane = tid & 63;
    const int itembase = blockIdx.x * 64 + wave * 16;

    char* const sbase = (char*)srows;

    // ---- stage: 16 rows per wave, each as a contiguous 2 KB burst ----
    #pragma unroll 8
    for (int r = 0; r < 16; ++r) {
        int item = itembase + r;
        int s = item / SEQ;
        int t = item - s * SEQ;
        int wid = words[s * TLEN + t + 1];
        const float* src = E + (size_t)wid * DDIM + lane * 8;
        float4 f0 = *(const float4*)(src);
        float4 f1 = *(const float4*)(src + 4);
        unsigned int q0, q1, q2, q3;
        asm("v_cvt_pk_bf16_f32 %0, %1, %2" : "=v"(q0) : "v"(f0.x), "v"(f0.y));
        asm("v_cvt_pk_bf16_f32 %0, %1, %2" : "=v"(q1) : "v"(f0.z), "v"(f0.w));
        asm("v_cvt_pk_bf16_f32 %0, %1, %2" : "=v"(q2) : "v"(f1.x), "v"(f1.y));
        asm("v_cvt_pk_bf16_f32 %0, %1, %2" : "=v"(q3) : "v"(f1.z), "v"(f1.w));
        int row  = wave * 16 + r;
        int boff = (lane * 16) ^ ((row & 7) << 4);   // XOR swizzle (involution)
        i32x4 q = {(int)q0, (int)q1, (int)q2, (int)q3};
        *(i32x4*)(sbase + row * 1024 + boff) = q;
    }

    // ---- MFMA: A-frag lane(c,g) = row c, shorts [32ks+8g .. +8) ----
    const int c = lane & 15;
    const int g = lane >> 4;
    const int myrow = wave * 16 + c;
    const char* rbase = sbase + myrow * 1024;
    const int rsw = (myrow & 7) << 4;

    f32x4 acc0 = {0,0,0,0}, acc1 = {0,0,0,0}, acc2 = {0,0,0,0}, acc3 = {0,0,0,0};

    #pragma unroll
    for (int ks = 0; ks < NKS; ++ks) {
        int boff = (64 * ks + 16 * g) ^ rsw;
        bf16x8 afrag = *(const bf16x8*)(rbase + boff);

        const bf16x8* bbase = (const bf16x8*)thp + (ks * 4) * 64 + lane;
        bf16x8 b0 = bbase[0];
        bf16x8 b1 = bbase[64];
        bf16x8 b2 = bbase[128];
        bf16x8 b3 = bbase[192];

        acc0 = __builtin_amdgcn_mfma_f32_16x16x32_bf16(afrag, b0, acc0, 0, 0, 0);
        acc1 = __builtin_amdgcn_mfma_f32_16x16x32_bf16(afrag, b1, acc1, 0, 0, 0);
        acc2 = __builtin_amdgcn_mfma_f32_16x16x32_bf16(afrag, b2, acc2, 0, 0, 0);
        acc3 = __builtin_amdgcn_mfma_f32_16x16x32_bf16(afrag, b3, acc3, 0, 0, 0);
    }

    // epilogue: C col = lane&15 (tag within 16-block), row = (lane>>4)*4+rr
    const int col = lane & 15;
    const int m0  = (lane >> 4) * 4;
    #pragma unroll
    for (int rr = 0; rr < 4; ++rr) {
        int item2 = itembase + m0 + rr;
        int s2 = item2 / SEQ;
        int t2 = item2 - s2 * SEQ;
        float* dst = eout + (((size_t)(s2 >> 4) * SEQ + t2) * 16 + (s2 & 15)) * KTAGS;
        dst[0 * 16 + col] = __expf(acc0[rr]);
        dst[1 * 16 + col] = __expf(acc1[rr]);
        dst[2 * 16 + col] = __expf(acc2[rr]);
        float v3 = (48 + col >= EOS_T) ? 1e-45f : __expf(acc3[rr]);
        dst[3 * 16 + col] = v3;
    }
}

// ---------------------------------------------------------------------------
// Kernel 2: forward recursion in matrix form, 16 sequences per 64-lane wave.
//   X_{t+1}(64x16) = (M^T . X_t) * E_t ; C -> next-B via permlane swaps.
//   8-deep register prefetch ring (32 loads in flight) hides L2/L3 latency.
// ---------------------------------------------------------------------------
__global__ __launch_bounds__(64) void fwd_kernel(
    const float* __restrict__ WA, const int* __restrict__ tags,
    const float* __restrict__ eout, float* __restrict__ out)
{
    const int blk  = blockIdx.x;       // 0..31, seqs blk*16..+15
    const int lane = threadIdx.x;
    const int g    = lane >> 4;        // lane group 0..3
    const int c    = lane & 15;        // seq within block (B/C col); A row

    // e tile (blk,t) is 4 KB contiguous at eout + (blk*SEQ+t)*1024
    const float* ep0 = eout + (size_t)blk * SEQ * 1024 + c * KTAGS + g * 4;

#define LD4R(Rr, tt)                                                        \
    {                                                                       \
        const float* p_ = ep0 + (size_t)(tt) * 1024;                        \
        Rr[0] = *(const float4*)(p_);                                       \
        Rr[1] = *(const float4*)(p_ + 16);                                  \
        Rr[2] = *(const float4*)(p_ + 32);                                  \
        Rr[3] = *(const float4*)(p_ + 48);                                  \
    }

    // fill the 8-deep ring FIRST so loads fly during the Af/expf prologue
    float4 R[8][4];
    #pragma unroll
    for (int i = 0; i < 8; ++i) LD4R(R[i], i);

    // ---- A-frags: Af[rb][h] = M^T[rb*16+c][h*32+g*8+j]; M^T row 63 zero ----
    bf16x8 Af[4][2];
    #pragma unroll
    for (int rb = 0; rb < 4; ++rb) {
        #pragma unroll
        for (int h = 0; h < 2; ++h) {
            short tmp[8];
            #pragma unroll
            for (int j = 0; j < 8; ++j) {
                float w = WA[(h * 32 + g * 8 + j) * KTAGS + rb * 16 + c];
                float v = (rb * 16 + c == BOS_T) ? 0.f : __expf(w);
                tmp[j] = f2bf(v);
            }
            Af[rb][h] = *(const bf16x8*)tmp;
        }
    }

    // ---- init X_0 = onehot(BOS=63) for every seq ----
    union { unsigned int u[4]; bf16x8 v; } qi0, qi1;
    qi0.u[0] = qi0.u[1] = qi0.u[2] = qi0.u[3] = 0u;
    qi1.u[0] = qi1.u[1] = qi1.u[2] = 0u;
    qi1.u[3] = (g == 3) ? 0x3F800000u : 0u;   // high16 = bf16(1.0)
    bf16x8 nb0 = qi0.v, nb1 = qi1.v;

    float logsum = 0.f;

#define STEP(E0, E1, E2, E3, RESC)                                          \
    {                                                                       \
        f32x4 zz = {0.f, 0.f, 0.f, 0.f};                                    \
        f32x4 c0 = __builtin_amdgcn_mfma_f32_16x16x32_bf16(Af[0][0], nb0, zz, 0, 0, 0); \
        c0 = __builtin_amdgcn_mfma_f32_16x16x32_bf16(Af[0][1], nb1, c0, 0, 0, 0); \
        f32x4 c1 = __builtin_amdgcn_mfma_f32_16x16x32_bf16(Af[1][0], nb0, zz, 0, 0, 0); \
        c1 = __builtin_amdgcn_mfma_f32_16x16x32_bf16(Af[1][1], nb1, c1, 0, 0, 0); \
        f32x4 c2 = __builtin_amdgcn_mfma_f32_16x16x32_bf16(Af[2][0], nb0, zz, 0, 0, 0); \
        c2 = __builtin_amdgcn_mfma_f32_16x16x32_bf16(Af[2][1], nb1, c2, 0, 0, 0); \
        f32x4 c3 = __builtin_amdgcn_mfma_f32_16x16x32_bf16(Af[3][0], nb0, zz, 0, 0, 0); \
        c3 = __builtin_amdgcn_mfma_f32_16x16x32_bf16(Af[3][1], nb1, c3, 0, 0, 0); \
        float m00 = c0[0]*E0.x, m01 = c0[1]*E0.y, m02 = c0[2]*E0.z, m03 = c0[3]*E0.w; \
        float m10 = c1[0]*E1.x, m11 = c1[1]*E1.y, m12 = c1[2]*E1.z, m13 = c1[3]*E1.w; \
        float m20 = c2[0]*E2.x, m21 = c2[1]*E2.y, m22 = c2[2]*E2.z, m23 = c2[3]*E2.w; \
        float m30 = c3[0]*E3.x, m31 = c3[1]*E3.y, m32 = c3[2]*E3.z, m33 = c3[3]*E3.w; \
        if (RESC) {                                                         \
            float mx = fmaxf(fmaxf(fmaxf(m00, m01), fmaxf(m02, m03)),       \
                             fmaxf(fmaxf(m10, m11), fmaxf(m12, m13)));      \
            mx = fmaxf(mx, fmaxf(fmaxf(m20, m21), fmaxf(m22, m23)));        \
            mx = fmaxf(mx, fmaxf(fmaxf(m30, m31), fmaxf(m32, m33)));        \
            mx = fmaxf(mx, __shfl_xor(mx, 16));                             \
            mx = fmaxf(mx, __shfl_xor(mx, 32));                             \
            float rs = __builtin_amdgcn_rcpf(mx);                           \
            m00 *= rs; m01 *= rs; m02 *= rs; m03 *= rs;                     \
            m10 *= rs; m11 *= rs; m12 *= rs; m13 *= rs;                     \
            m20 *= rs; m21 *= rs; m22 *= rs; m23 *= rs;                     \
            m30 *= rs; m31 *= rs; m32 *= rs; m33 *= rs;                     \
            logsum += __logf(mx);                                           \
        }                                                                   \
        unsigned int p00, p01, p10, p11, p20, p21, p30, p31;                \
        asm("v_cvt_pk_bf16_f32 %0, %1, %2" : "=v"(p00) : "v"(m00), "v"(m01)); \
        asm("v_cvt_pk_bf16_f32 %0, %1, %2" : "=v"(p01) : "v"(m02), "v"(m03)); \
        asm("v_cvt_pk_bf16_f32 %0, %1, %2" : "=v"(p10) : "v"(m10), "v"(m11)); \
        asm("v_cvt_pk_bf16_f32 %0, %1, %2" : "=v"(p11) : "v"(m12), "v"(m13)); \
        asm("v_cvt_pk_bf16_f32 %0, %1, %2" : "=v"(p20) : "v"(m20), "v"(m21)); \
        asm("v_cvt_pk_bf16_f32 %0, %1, %2" : "=v"(p21) : "v"(m22), "v"(m23)); \
        asm("v_cvt_pk_bf16_f32 %0, %1, %2" : "=v"(p30) : "v"(m30), "v"(m31)); \
        asm("v_cvt_pk_bf16_f32 %0, %1, %2" : "=v"(p31) : "v"(m32), "v"(m33)); \
        unsigned int a0 = p00, b0 = p10;                                    \
        asm volatile("v_permlane32_swap_b32 %0, %1" : "+v"(a0), "+v"(b0));  \
        asm volatile("v_permlane16_swap_b32 %0, %1" : "+v"(a0), "+v"(b0));  \
        unsigned int a1 = p01, b1 = p11;                                    \
        asm volatile("v_permlane32_swap_b32 %0, %1" : "+v"(a1), "+v"(b1));  \
        asm volatile("v_permlane16_swap_b32 %0, %1" : "+v"(a1), "+v"(b1));  \
        unsigned int a2 = p20, b2 = p30;                                    \
        asm volatile("v_permlane32_swap_b32 %0, %1" : "+v"(a2), "+v"(b2));  \
        asm volatile("v_permlane16_swap_b32 %0, %1" : "+v"(a2), "+v"(b2));  \
        unsigned int a3 = p21, b3 = p31;                                    \
        asm volatile("v_permlane32_swap_b32 %0, %1" : "+v"(a3), "+v"(b3));  \
        asm volatile("v_permlane16_swap_b32 %0, %1" : "+v"(a3), "+v"(b3));  \
        union { unsigned int u[4]; bf16x8 v; } q0_, q1_;                    \
        q0_.u[0] = a0; q0_.u[1] = a1; q0_.u[2] = b0; q0_.u[3] = b1;         \
        q1_.u[0] = a2; q1_.u[1] = a3; q1_.u[2] = b2; q1_.u[3] = b3;         \
        nb0 = q0_.v; nb1 = q1_.v;                                           \
    }

    // main loop: steps 0..119, ring refilled 8 ahead (clamped)
    for (int t = 0; t < 120; t += 8) {
        #pragma unroll
        for (int i = 0; i < 8; ++i) {
            bool rsc = ((t & 8) != 0) && (i == 7);   // after steps 15,31,...,111
            STEP(R[i][0], R[i][1], R[i][2], R[i][3], rsc);
            int pt = t + 8 + i;
            if (pt > SEQ - 1) pt = SEQ - 1;
            LD4R(R[i], pt);
        }
    }
    // tail: steps 120..125 (growth since step 111 <= ~117^15: safe in fp32)
    #pragma unroll
    for (int i = 0; i < 6; ++i) {
        STEP(R[i][0], R[i][1], R[i][2], R[i][3], false);
    }

    // ---- final transition into EOS: tile rb=3, row 14 => g==3, reg 2 ----
    f32x4 zz = {0.f, 0.f, 0.f, 0.f};
    f32x4 cF = __builtin_amdgcn_mfma_f32_16x16x32_bf16(Af[3][0], nb0, zz, 0, 0, 0);
    cF = __builtin_amdgcn_mfma_f32_16x16x32_bf16(Af[3][1], nb1, cF, 0, 0, 0);
    float unsup = __logf(cF[2]) + logsum;    // valid on lanes 48..63 (seq = c)

    // ---- tagged pass: 4 lanes per seq ----
    const int sl = lane >> 2;          // seq within block
    const int q  = lane & 3;
    const int* trs = tags + (size_t)(blk * 16 + sl) * TLEN;
    float tsum = 0.f;
    #pragma unroll 4
    for (int m = 0; m < 32; ++m) {
        int t = 1 + q + 4 * m;
        if (t <= SEQ) {
            int cur  = trs[t];
            int prev = (t == 1) ? BOS_T : trs[t - 1];
            tsum += WA[prev * KTAGS + cur]
                  + __logf(eout[(((size_t)blk * SEQ + (t - 1)) * 16 + sl) * KTAGS + cur]);
        }
    }
    tsum += __shfl_xor(tsum, 1);
    tsum += __shfl_xor(tsum, 2);
    float tagged = tsum + WA[trs[SEQ] * KTAGS + EOS_T];

    // route seq c's tagged value to lane 48+c and store
    float tg = __shfl(tagged, c * 4);
    if (lane >= 48) out[blk * 16 + c] = tg - unsup;

#undef LD4R
#undef STEP
}

// ---------------------------------------------------------------------------
extern "C" void kernel_launch(void* const* d_in, const int* in_sizes, int n_in,
                              void* d_out, int out_size, void* d_ws, size_t ws_size,
                              hipStream_t stream) {
    const float* WA     = (const float*)d_in[0];
    const float* ThetaB = (const float*)d_in[1];
    const float* E      = (const float*)d_in[2];
    const int*   words  = (const int*)d_in[3];
    const int*   tags   = (const int*)d_in[4];
    float*       out    = (float*)d_out;

    float* eout = (float*)d_ws;                          // 16,515,072 B
    short* thp  = (short*)((char*)d_ws + 16515072);      // 65,536 B

    pack_theta_kernel<<<dim3(16), dim3(256), 0, stream>>>(ThetaB, thp);
    emit_kernel<<<dim3(NITEMS / 64), dim3(256), 0, stream>>>(E, words, thp, eout);
    fwd_kernel<<<dim3(BSEQ / 16), dim3(64), 0, stream>>>(WA, tags, eout, out);
}

// Round 8
// 71.481 us; speedup vs baseline: 1.0782x; 1.0782x over previous
//
#include <hip/hip_runtime.h>
#include <hip/hip_bf16.h>
#include <cstddef>
#include <cstdint>

#define KTAGS 64
#define DDIM  512
#define TLEN  128
#define BSEQ  512
#define SEQ   126          // real word positions t = 1..126
#define BOS_T 63
#define EOS_T 62
#define NITEMS (BSEQ * SEQ)   // 64512
#define NKS   (DDIM / 32)     // 16 K-steps of 32

typedef __attribute__((ext_vector_type(8))) short bf16x8;   // 8 bf16 = 4 VGPRs
typedef __attribute__((ext_vector_type(4))) float f32x4;
typedef __attribute__((ext_vector_type(4))) int   i32x4;

__device__ __forceinline__ short f2bf(float f) {
    uint32_t u = __float_as_uint(f);
    u += 0x7fffu + ((u >> 16) & 1u);       // RTNE
    return (short)(u >> 16);
}

// ---------------------------------------------------------------------------
// Kernel 0: pack ThetaB (f32 [64][512]) into bf16 MFMA B-frag order.
// frag idx = (ks*4+g)*64 + lane ; holds Th[g*16+(lane&15)][ks*32+(lane>>4)*8+j]
// ---------------------------------------------------------------------------
__global__ __launch_bounds__(256) void pack_theta_kernel(
    const float* __restrict__ Th, short* __restrict__ thp)
{
    int idx  = blockIdx.x * 256 + threadIdx.x;   // 0..4095
    int lane = idx & 63;
    int gg   = (idx >> 6) & 3;
    int ks   = idx >> 8;
    int tag  = gg * 16 + (lane & 15);
    int kb   = ks * 32 + (lane >> 4) * 8;
    const float* src = Th + (size_t)tag * DDIM + kb;
    short tmp[8];
    #pragma unroll
    for (int j = 0; j < 8; ++j) tmp[j] = f2bf(src[j]);
    *(i32x4*)(thp + (size_t)idx * 8) = *(const i32x4*)tmp;
}

// ---------------------------------------------------------------------------
// Kernel 1 v3: e[(s/16)][t][s%16][tag] = exp(dot(E[words[s][t+1]], ThetaB[tag]))
// Burst gather at high occupancy: each E row fetched as two contiguous 1 KB
// wave-loads (lane x 16 B), cvt_pk'd to bf16, staged in a 32 KB XOR-swizzled
// per-wave-disjoint LDS region (no barriers). K-loop split in two halves.
// ---------------------------------------------------------------------------
__global__ __launch_bounds__(256) void emit_kernel(
    const float* __restrict__ E, const int* __restrict__ words,
    const short* __restrict__ thp, float* __restrict__ eout)
{
    __shared__ short srows[4 * 16 * 256];   // 32 KB: wave regions of 16 rows x 512 B

    const int tid  = threadIdx.x;
    const int wave = tid >> 6;
    const int lane = tid & 63;
    const int itembase = blockIdx.x * 64 + wave * 16;

    char* const wreg = (char*)srows + wave * 8192;

    // lane c (c = lane&15) computes row c's word id; readlane broadcasts it
    int myitem = itembase + (lane & 15);
    int ms = myitem / SEQ;
    int mt = myitem - ms * SEQ;
    int mywid = words[ms * TLEN + mt + 1];

#define STAGE(h)                                                            \
    {                                                                       \
        _Pragma("unroll")                                                   \
        for (int r = 0; r < 16; ++r) {                                      \
            int wid_r = __builtin_amdgcn_readlane(mywid, r);                \
            const float* src = E + (size_t)wid_r * DDIM + (h) * 256 + lane * 4; \
            float4 f = *(const float4*)src;                                 \
            unsigned int d0, d1;                                            \
            asm("v_cvt_pk_bf16_f32 %0, %1, %2" : "=v"(d0) : "v"(f.x), "v"(f.y)); \
            asm("v_cvt_pk_bf16_f32 %0, %1, %2" : "=v"(d1) : "v"(f.z), "v"(f.w)); \
            int boff = (lane * 8) ^ ((r & 7) << 4);                         \
            unsigned long long dd = ((unsigned long long)d1 << 32) | d0;    \
            *(unsigned long long*)(wreg + r * 512 + boff) = dd;             \
        }                                                                   \
    }

    const int c = lane & 15;
    const int g = lane >> 4;
    const char* rbase = wreg + c * 512;
    const int rsw = (c & 7) << 4;

    f32x4 acc0 = {0,0,0,0}, acc1 = {0,0,0,0}, acc2 = {0,0,0,0}, acc3 = {0,0,0,0};

#define MFMA_HALF(h)                                                        \
    {                                                                       \
        _Pragma("unroll")                                                   \
        for (int kk = 0; kk < 8; ++kk) {                                    \
            int ks = (h) * 8 + kk;                                          \
            bf16x8 afrag = *(const bf16x8*)(rbase + ((kk * 64 + g * 16) ^ rsw)); \
            const bf16x8* bbase = (const bf16x8*)thp + (ks * 4) * 64 + lane; \
            bf16x8 b0 = bbase[0];                                           \
            bf16x8 b1 = bbase[64];                                          \
            bf16x8 b2 = bbase[128];                                         \
            bf16x8 b3 = bbase[192];                                         \
            acc0 = __builtin_amdgcn_mfma_f32_16x16x32_bf16(afrag, b0, acc0, 0, 0, 0); \
            acc1 = __builtin_amdgcn_mfma_f32_16x16x32_bf16(afrag, b1, acc1, 0, 0, 0); \
            acc2 = __builtin_amdgcn_mfma_f32_16x16x32_bf16(afrag, b2, acc2, 0, 0, 0); \
            acc3 = __builtin_amdgcn_mfma_f32_16x16x32_bf16(afrag, b3, acc3, 0, 0, 0); \
        }                                                                   \
    }

    STAGE(0);
    MFMA_HALF(0);
    STAGE(1);
    MFMA_HALF(1);

#undef STAGE
#undef MFMA_HALF

    // epilogue: C col = lane&15 (tag within 16-block), row = (lane>>4)*4+rr
    const int col = lane & 15;
    const int m0  = (lane >> 4) * 4;
    #pragma unroll
    for (int rr = 0; rr < 4; ++rr) {
        int item2 = itembase + m0 + rr;
        int s2 = item2 / SEQ;
        int t2 = item2 - s2 * SEQ;
        float* dst = eout + (((size_t)(s2 >> 4) * SEQ + t2) * 16 + (s2 & 15)) * KTAGS;
        dst[0 * 16 + col] = __expf(acc0[rr]);
        dst[1 * 16 + col] = __expf(acc1[rr]);
        dst[2 * 16 + col] = __expf(acc2[rr]);
        float v3 = (48 + col >= EOS_T) ? 1e-45f : __expf(acc3[rr]);
        dst[3 * 16 + col] = v3;
    }
}

// ---------------------------------------------------------------------------
// Kernel 2: forward recursion in matrix form, 16 sequences per 64-lane wave.
//   X_{t+1}(64x16) = (M^T . X_t) * E_t ; C -> next-B via permlane swaps.
//   8-deep register prefetch ring (32 loads in flight) hides L2/L3 latency.
// ---------------------------------------------------------------------------
__global__ __launch_bounds__(64) void fwd_kernel(
    const float* __restrict__ WA, const int* __restrict__ tags,
    const float* __restrict__ eout, float* __restrict__ out)
{
    const int blk  = blockIdx.x;       // 0..31, seqs blk*16..+15
    const int lane = threadIdx.x;
    const int g    = lane >> 4;        // lane group 0..3
    const int c    = lane & 15;        // seq within block (B/C col); A row

    // e tile (blk,t) is 4 KB contiguous at eout + (blk*SEQ+t)*1024
    const float* ep0 = eout + (size_t)blk * SEQ * 1024 + c * KTAGS + g * 4;

#define LD4R(Rr, tt)                                                        \
    {                                                                       \
        const float* p_ = ep0 + (size_t)(tt) * 1024;                        \
        Rr[0] = *(const float4*)(p_);                                       \
        Rr[1] = *(const float4*)(p_ + 16);                                  \
        Rr[2] = *(const float4*)(p_ + 32);                                  \
        Rr[3] = *(const float4*)(p_ + 48);                                  \
    }

    // fill the 8-deep ring FIRST so loads fly during the Af/expf prologue
    float4 R[8][4];
    #pragma unroll
    for (int i = 0; i < 8; ++i) LD4R(R[i], i);

    // ---- A-frags: Af[rb][h] = M^T[rb*16+c][h*32+g*8+j]; M^T row 63 zero ----
    bf16x8 Af[4][2];
    #pragma unroll
    for (int rb = 0; rb < 4; ++rb) {
        #pragma unroll
        for (int h = 0; h < 2; ++h) {
            short tmp[8];
            #pragma unroll
            for (int j = 0; j < 8; ++j) {
                float w = WA[(h * 32 + g * 8 + j) * KTAGS + rb * 16 + c];
                float v = (rb * 16 + c == BOS_T) ? 0.f : __expf(w);
                tmp[j] = f2bf(v);
            }
            Af[rb][h] = *(const bf16x8*)tmp;
        }
    }

    // ---- init X_0 = onehot(BOS=63) for every seq ----
    union { unsigned int u[4]; bf16x8 v; } qi0, qi1;
    qi0.u[0] = qi0.u[1] = qi0.u[2] = qi0.u[3] = 0u;
    qi1.u[0] = qi1.u[1] = qi1.u[2] = 0u;
    qi1.u[3] = (g == 3) ? 0x3F800000u : 0u;   // high16 = bf16(1.0)
    bf16x8 nb0 = qi0.v, nb1 = qi1.v;

    float logsum = 0.f;

#define STEP(E0, E1, E2, E3, RESC)                                          \
    {                                                                       \
        f32x4 zz = {0.f, 0.f, 0.f, 0.f};                                    \
        f32x4 c0 = __builtin_amdgcn_mfma_f32_16x16x32_bf16(Af[0][0], nb0, zz, 0, 0, 0); \
        c0 = __builtin_amdgcn_mfma_f32_16x16x32_bf16(Af[0][1], nb1, c0, 0, 0, 0); \
        f32x4 c1 = __builtin_amdgcn_mfma_f32_16x16x32_bf16(Af[1][0], nb0, zz, 0, 0, 0); \
        c1 = __builtin_amdgcn_mfma_f32_16x16x32_bf16(Af[1][1], nb1, c1, 0, 0, 0); \
        f32x4 c2 = __builtin_amdgcn_mfma_f32_16x16x32_bf16(Af[2][0], nb0, zz, 0, 0, 0); \
        c2 = __builtin_amdgcn_mfma_f32_16x16x32_bf16(Af[2][1], nb1, c2, 0, 0, 0); \
        f32x4 c3 = __builtin_amdgcn_mfma_f32_16x16x32_bf16(Af[3][0], nb0, zz, 0, 0, 0); \
        c3 = __builtin_amdgcn_mfma_f32_16x16x32_bf16(Af[3][1], nb1, c3, 0, 0, 0); \
        float m00 = c0[0]*E0.x, m01 = c0[1]*E0.y, m02 = c0[2]*E0.z, m03 = c0[3]*E0.w; \
        float m10 = c1[0]*E1.x, m11 = c1[1]*E1.y, m12 = c1[2]*E1.z, m13 = c1[3]*E1.w; \
        float m20 = c2[0]*E2.x, m21 = c2[1]*E2.y, m22 = c2[2]*E2.z, m23 = c2[3]*E2.w; \
        float m30 = c3[0]*E3.x, m31 = c3[1]*E3.y, m32 = c3[2]*E3.z, m33 = c3[3]*E3.w; \
        if (RESC) {                                                         \
            float mx = fmaxf(fmaxf(fmaxf(m00, m01), fmaxf(m02, m03)),       \
                             fmaxf(fmaxf(m10, m11), fmaxf(m12, m13)));      \
            mx = fmaxf(mx, fmaxf(fmaxf(m20, m21), fmaxf(m22, m23)));        \
            mx = fmaxf(mx, fmaxf(fmaxf(m30, m31), fmaxf(m32, m33)));        \
            mx = fmaxf(mx, __shfl_xor(mx, 16));                             \
            mx = fmaxf(mx, __shfl_xor(mx, 32));                             \
            float rs = __builtin_amdgcn_rcpf(mx);                           \
            m00 *= rs; m01 *= rs; m02 *= rs; m03 *= rs;                     \
            m10 *= rs; m11 *= rs; m12 *= rs; m13 *= rs;                     \
            m20 *= rs; m21 *= rs; m22 *= rs; m23 *= rs;                     \
            m30 *= rs; m31 *= rs; m32 *= rs; m33 *= rs;                     \
            logsum += __logf(mx);                                           \
        }                                                                   \
        unsigned int p00, p01, p10, p11, p20, p21, p30, p31;                \
        asm("v_cvt_pk_bf16_f32 %0, %1, %2" : "=v"(p00) : "v"(m00), "v"(m01)); \
        asm("v_cvt_pk_bf16_f32 %0, %1, %2" : "=v"(p01) : "v"(m02), "v"(m03)); \
        asm("v_cvt_pk_bf16_f32 %0, %1, %2" : "=v"(p10) : "v"(m10), "v"(m11)); \
        asm("v_cvt_pk_bf16_f32 %0, %1, %2" : "=v"(p11) : "v"(m12), "v"(m13)); \
        asm("v_cvt_pk_bf16_f32 %0, %1, %2" : "=v"(p20) : "v"(m20), "v"(m21)); \
        asm("v_cvt_pk_bf16_f32 %0, %1, %2" : "=v"(p21) : "v"(m22), "v"(m23)); \
        asm("v_cvt_pk_bf16_f32 %0, %1, %2" : "=v"(p30) : "v"(m30), "v"(m31)); \
        asm("v_cvt_pk_bf16_f32 %0, %1, %2" : "=v"(p31) : "v"(m32), "v"(m33)); \
        unsigned int a0 = p00, b0 = p10;                                    \
        asm volatile("v_permlane32_swap_b32 %0, %1" : "+v"(a0), "+v"(b0));  \
        asm volatile("v_permlane16_swap_b32 %0, %1" : "+v"(a0), "+v"(b0));  \
        unsigned int a1 = p01, b1 = p11;                                    \
        asm volatile("v_permlane32_swap_b32 %0, %1" : "+v"(a1), "+v"(b1));  \
        asm volatile("v_permlane16_swap_b32 %0, %1" : "+v"(a1), "+v"(b1));  \
        unsigned int a2 = p20, b2 = p30;                                    \
        asm volatile("v_permlane32_swap_b32 %0, %1" : "+v"(a2), "+v"(b2));  \
        asm volatile("v_permlane16_swap_b32 %0, %1" : "+v"(a2), "+v"(b2));  \
        unsigned int a3 = p21, b3 = p31;                                    \
        asm volatile("v_permlane32_swap_b32 %0, %1" : "+v"(a3), "+v"(b3));  \
        asm volatile("v_permlane16_swap_b32 %0, %1" : "+v"(a3), "+v"(b3));  \
        union { unsigned int u[4]; bf16x8 v; } q0_, q1_;                    \
        q0_.u[0] = a0; q0_.u[1] = a1; q0_.u[2] = b0; q0_.u[3] = b1;         \
        q1_.u[0] = a2; q1_.u[1] = a3; q1_.u[2] = b2; q1_.u[3] = b3;         \
        nb0 = q0_.v; nb1 = q1_.v;                                           \
    }

    // main loop: steps 0..119, ring refilled 8 ahead (clamped)
    for (int t = 0; t < 120; t += 8) {
        #pragma unroll
        for (int i = 0; i < 8; ++i) {
            bool rsc = ((t & 8) != 0) && (i == 7);   // after steps 15,31,...,111
            STEP(R[i][0], R[i][1], R[i][2], R[i][3], rsc);
            int pt = t + 8 + i;
            if (pt > SEQ - 1) pt = SEQ - 1;
            LD4R(R[i], pt);
        }
    }
    // tail: steps 120..125 (growth since step 111 <= ~117^15: safe in fp32)
    #pragma unroll
    for (int i = 0; i < 6; ++i) {
        STEP(R[i][0], R[i][1], R[i][2], R[i][3], false);
    }

    // ---- final transition into EOS: tile rb=3, row 14 => g==3, reg 2 ----
    f32x4 zz = {0.f, 0.f, 0.f, 0.f};
    f32x4 cF = __builtin_amdgcn_mfma_f32_16x16x32_bf16(Af[3][0], nb0, zz, 0, 0, 0);
    cF = __builtin_amdgcn_mfma_f32_16x16x32_bf16(Af[3][1], nb1, cF, 0, 0, 0);
    float unsup = __logf(cF[2]) + logsum;    // valid on lanes 48..63 (seq = c)

    // ---- tagged pass: 4 lanes per seq ----
    const int sl = lane >> 2;          // seq within block
    const int q  = lane & 3;
    const int* trs = tags + (size_t)(blk * 16 + sl) * TLEN;
    float tsum = 0.f;
    #pragma unroll 4
    for (int m = 0; m < 32; ++m) {
        int t = 1 + q + 4 * m;
        if (t <= SEQ) {
            int cur  = trs[t];
            int prev = (t == 1) ? BOS_T : trs[t - 1];
            tsum += WA[prev * KTAGS + cur]
                  + __logf(eout[(((size_t)blk * SEQ + (t - 1)) * 16 + sl) * KTAGS + cur]);
        }
    }
    tsum += __shfl_xor(tsum, 1);
    tsum += __shfl_xor(tsum, 2);
    float tagged = tsum + WA[trs[SEQ] * KTAGS + EOS_T];

    // route seq c's tagged value to lane 48+c and store
    float tg = __shfl(tagged, c * 4);
    if (lane >= 48) out[blk * 16 + c] = tg - unsup;

#undef LD4R
#undef STEP
}

// ---------------------------------------------------------------------------
extern "C" void kernel_launch(void* const* d_in, const int* in_sizes, int n_in,
                              void* d_out, int out_size, void* d_ws, size_t ws_size,
                              hipStream_t stream) {
    const float* WA     = (const float*)d_in[0];
    const float* ThetaB = (const float*)d_in[1];
    const float* E      = (const float*)d_in[2];
    const int*   words  = (const int*)d_in[3];
    const int*   tags   = (const int*)d_in[4];
    float*       out    = (float*)d_out;

    float* eout = (float*)d_ws;                          // 16,515,072 B
    short* thp  = (short*)((char*)d_ws + 16515072);      // 65,536 B

    pack_theta_kernel<<<dim3(16), dim3(256), 0, stream>>>(ThetaB, thp);
    emit_kernel<<<dim3(NITEMS / 64), dim3(256), 0, stream>>>(E, words, thp, eout);
    fwd_kernel<<<dim3(BSEQ / 16), dim3(64), 0, stream>>>(WA, tags, eout, out);
}